// Round 4
// baseline (131.370 us; speedup 1.0000x reference)
//
#include <hip/hip_runtime.h>
#include <hip/hip_bf16.h>
#include <math.h>

// SPP max-pool pyramid: x [B=32, H=64, W=64, C=512] f32 (NHWC, C innermost)
// scales (1,1),(2,2),(4,4),(8,8). Output row layout per batch (43520 floats):
//   [0,512)        : 1x1 scale
//   [512,2560)     : 2x2 scale, (i2*2+j2)*512 + c
//   [2560,10752)   : 4x4 scale, (i4*4+j4)*512 + c
//   [10752,43520)  : 8x8 scale, (i8*8+j8)*512 + c
// All bin sizes divide 64 evenly, so uniform bins (last-bin-extends is a no-op).
//
// Single fused kernel: 512 blocks = (b, i4, j4). Each block streams its 16x16
// patch (exactly-once input read, nontemporal), writes its four s8 bins and
// one s4 bin; the last of a batch's 16 blocks (atomic ticket in d_ws) derives
// s2 + s1 from the 16 s4 bins (32 KB, L2-resident).

#define C_F4 128          // 512 channels / 4
#define ROW_OUT 43520     // 85 * 512
#define S8_OFF 10752
#define S4_OFF 2560
#define S2_OFF 512

typedef float vf4 __attribute__((ext_vector_type(4)));

static __device__ __forceinline__ vf4 vmax(vf4 a, vf4 b) {
    vf4 r;
    r.x = fmaxf(a.x, b.x);
    r.y = fmaxf(a.y, b.y);
    r.z = fmaxf(a.z, b.z);
    r.w = fmaxf(a.w, b.w);
    return r;
}

__global__ __launch_bounds__(256) void spp_fused(const float* __restrict__ x,
                                                 float* __restrict__ out,
                                                 int* __restrict__ cnt) {
    const int blk = blockIdx.x;           // 0..511
    const int b   = blk >> 4;
    const int rem = blk & 15;
    const int i4  = rem >> 2;
    const int j4  = rem & 3;
    const int tid = threadIdx.x;          // 0..255
    const int s   = tid >> 7;             // band 0/1 within the 16-row patch
    const int c4  = tid & 127;

    const int row0 = i4 * 16 + s * 8;
    const vf4* src = reinterpret_cast<const vf4*>(x)
                   + (size_t)((b * 64 + row0) * 64 + j4 * 16) * C_F4 + c4;
    // vf4 strides: next col = 128, next row = 64*128 = 8192

    vf4 m0 = __builtin_nontemporal_load(src);
    vf4 m1 = __builtin_nontemporal_load(src + 8 * 128);
    #pragma unroll 2
    for (int h = 0; h < 8; ++h) {
        #pragma unroll
        for (int w = 0; w < 8; ++w) {
            if (h == 0 && w == 0) continue;
            m0 = vmax(m0, __builtin_nontemporal_load(src + h * 8192 + w * 128));
            m1 = vmax(m1, __builtin_nontemporal_load(src + h * 8192 + (w + 8) * 128));
        }
    }

    float* row = out + (size_t)b * ROW_OUT;
    const int i8 = 2 * i4 + s;
    const int j8 = 2 * j4;
    reinterpret_cast<vf4*>(row + S8_OFF + (i8 * 8 + j8) * 512)[c4]     = m0;
    reinterpret_cast<vf4*>(row + S8_OFF + (i8 * 8 + j8 + 1) * 512)[c4] = m1;

    __shared__ vf4 ls[2][128];
    ls[s][c4] = vmax(m0, m1);
    __syncthreads();
    if (s == 0) {
        vf4 v4 = vmax(ls[0][c4], ls[1][c4]);
        reinterpret_cast<vf4*>(row + S4_OFF + (i4 * 4 + j4) * 512)[c4] = v4;
    }

    // ---- last-block-per-batch tail: s2 + s1 ----
    __shared__ int lastflag;
    __threadfence();              // release: make our s8/s4 stores device-visible
    __syncthreads();              // all threads' stores fenced before signaling
    if (tid == 0)
        lastflag = (atomicAdd(&cnt[b], 1) == 15) ? 1 : 0;
    __syncthreads();
    if (lastflag) {               // block-uniform
        __threadfence();          // acquire: observe the other 15 blocks' s4
        const vf4* p4 = reinterpret_cast<const vf4*>(row + S4_OFF) + c4;
        vf4 acc;
        #pragma unroll
        for (int k = 0; k < 2; ++k) {
            const int q  = 2 * s + k;       // this thread covers quadrants 2s, 2s+1
            const int i2 = q >> 1;
            const int j2 = q & 1;
            vf4 m =        p4[((2 * i2)     * 4 + 2 * j2)     * C_F4];
            m = vmax(m,    p4[((2 * i2)     * 4 + 2 * j2 + 1) * C_F4]);
            m = vmax(m,    p4[((2 * i2 + 1) * 4 + 2 * j2)     * C_F4]);
            m = vmax(m,    p4[((2 * i2 + 1) * 4 + 2 * j2 + 1) * C_F4]);
            reinterpret_cast<vf4*>(row + S2_OFF + q * 512)[c4] = m;
            acc = (k == 0) ? m : vmax(acc, m);
        }
        ls[s][c4] = acc;
        __syncthreads();
        if (s == 0)
            reinterpret_cast<vf4*>(row)[c4] = vmax(ls[0][c4], ls[1][c4]);
    }
}

extern "C" void kernel_launch(void* const* d_in, const int* in_sizes, int n_in,
                              void* d_out, int out_size, void* d_ws, size_t ws_size,
                              hipStream_t stream) {
    const float* x = (const float*)d_in[0];
    float* out = (float*)d_out;
    int* cnt = (int*)d_ws;

    hipMemsetAsync(cnt, 0, 32 * sizeof(int), stream);   // per-batch tickets
    spp_fused<<<512, 256, 0, stream>>>(x, out, cnt);
}

// Round 5
// 47.723 us; speedup vs baseline: 2.7528x; 2.7528x over previous
//
#include <hip/hip_runtime.h>
#include <hip/hip_bf16.h>
#include <math.h>

// SPP max-pool pyramid: x [B=32, H=64, W=64, C=512] f32 (NHWC, C innermost)
// scales (1,1),(2,2),(4,4),(8,8). Output row layout per batch (43520 floats):
//   [0,512)        : 1x1 scale
//   [512,2560)     : 2x2 scale, (i2*2+j2)*512 + c
//   [2560,10752)   : 4x4 scale, (i4*4+j4)*512 + c
//   [10752,43520)  : 8x8 scale, (i8*8+j8)*512 + c
// All bin sizes divide 64 evenly, so uniform bins (last-bin-extends is a no-op).
//
// Two dispatches (single-kernel fusion with cross-block combine regressed
// 47->131 us: device-scope fences force per-XCD L2 writeback/invalidate on
// gfx950 — kernel boundary is the cheap coherence point).

#define C_F4 128          // 512 channels / 4
#define ROW_OUT 43520     // 85 * 512
#define S8_OFF 10752
#define S4_OFF 2560
#define S2_OFF 512

typedef float vf4 __attribute__((ext_vector_type(4)));

static __device__ __forceinline__ vf4 vmax(vf4 a, vf4 b) {
    vf4 r;
    r.x = fmaxf(a.x, b.x);
    r.y = fmaxf(a.y, b.y);
    r.z = fmaxf(a.z, b.z);
    r.w = fmaxf(a.w, b.w);
    return r;
}

// Kernel 1: one block per (b, i4, j4) = 512 blocks x 256 threads.
// Thread = (s, c4): s picks the top/bottom 8-row band of the 16x16 patch.
// Nontemporal input loads (exactly-once, 268 MB > L3) and nontemporal s8
// stores (never re-read on device) keep L2 clean for the s4 hand-off.
__global__ __launch_bounds__(256) void spp_pool84(const float* __restrict__ x,
                                                  float* __restrict__ out) {
    const int blk = blockIdx.x;           // 0..511
    const int b   = blk >> 4;
    const int rem = blk & 15;
    const int i4  = rem >> 2;
    const int j4  = rem & 3;
    const int tid = threadIdx.x;          // 0..255
    const int s   = tid >> 7;             // band 0/1
    const int c4  = tid & 127;

    const int row0 = i4 * 16 + s * 8;
    const vf4* src = reinterpret_cast<const vf4*>(x)
                   + (size_t)((b * 64 + row0) * 64 + j4 * 16) * C_F4 + c4;
    // vf4 strides: next col = 128, next row = 64*128 = 8192

    vf4 m0 = __builtin_nontemporal_load(src);
    vf4 m1 = __builtin_nontemporal_load(src + 8 * 128);
    #pragma unroll 2
    for (int h = 0; h < 8; ++h) {
        #pragma unroll
        for (int w = 0; w < 8; ++w) {
            if (h == 0 && w == 0) continue;
            m0 = vmax(m0, __builtin_nontemporal_load(src + h * 8192 + w * 128));
            m1 = vmax(m1, __builtin_nontemporal_load(src + h * 8192 + (w + 8) * 128));
        }
    }

    float* row = out + (size_t)b * ROW_OUT;
    const int i8 = 2 * i4 + s;
    const int j8 = 2 * j4;
    __builtin_nontemporal_store(m0, reinterpret_cast<vf4*>(row + S8_OFF + (i8 * 8 + j8) * 512) + c4);
    __builtin_nontemporal_store(m1, reinterpret_cast<vf4*>(row + S8_OFF + (i8 * 8 + j8 + 1) * 512) + c4);

    __shared__ vf4 ls[2][128];
    ls[s][c4] = vmax(m0, m1);
    __syncthreads();
    if (s == 0) {
        vf4 v4 = vmax(ls[0][c4], ls[1][c4]);
        reinterpret_cast<vf4*>(row + S4_OFF + (i4 * 4 + j4) * 512)[c4] = v4;
    }
}

// Kernel 2: derive 2x2 / 1x1 from the 4x4 scale (1 MB, cache-hot).
// One block per batch, 512 threads = (quadrant q, c4); 4 loads per thread.
__global__ __launch_bounds__(512) void spp_tail(float* __restrict__ out) {
    const int b   = blockIdx.x;           // 0..31
    const int tid = threadIdx.x;          // 0..511
    const int q   = tid >> 7;             // quadrant 0..3
    const int c4  = tid & 127;
    const int i2  = q >> 1;
    const int j2  = q & 1;

    float* row = out + (size_t)b * ROW_OUT;
    const vf4* p4 = reinterpret_cast<const vf4*>(row + S4_OFF) + c4;

    vf4 m =     p4[((2 * i2)     * 4 + 2 * j2)     * C_F4];
    m = vmax(m, p4[((2 * i2)     * 4 + 2 * j2 + 1) * C_F4]);
    m = vmax(m, p4[((2 * i2 + 1) * 4 + 2 * j2)     * C_F4]);
    m = vmax(m, p4[((2 * i2 + 1) * 4 + 2 * j2 + 1) * C_F4]);

    reinterpret_cast<vf4*>(row + S2_OFF + q * 512)[c4] = m;

    __shared__ vf4 ls[4][128];
    ls[q][c4] = m;
    __syncthreads();
    if (q == 0) {
        vf4 v1 = vmax(vmax(ls[0][c4], ls[1][c4]),
                      vmax(ls[2][c4], ls[3][c4]));
        reinterpret_cast<vf4*>(row)[c4] = v1;
    }
}

extern "C" void kernel_launch(void* const* d_in, const int* in_sizes, int n_in,
                              void* d_out, int out_size, void* d_ws, size_t ws_size,
                              hipStream_t stream) {
    const float* x = (const float*)d_in[0];
    float* out = (float*)d_out;

    spp_pool84<<<512, 256, 0, stream>>>(x, out);
    spp_tail<<<32, 512, 0, stream>>>(out);
}

// Round 6
// 46.113 us; speedup vs baseline: 2.8489x; 1.0349x over previous
//
#include <hip/hip_runtime.h>
#include <hip/hip_bf16.h>
#include <math.h>

// SPP max-pool pyramid: x [B=32, H=64, W=64, C=512] f32 (NHWC, C innermost)
// scales (1,1),(2,2),(4,4),(8,8). Output row layout per batch (43520 floats):
//   [0,512)        : 1x1 scale
//   [512,2560)     : 2x2 scale, (i2*2+j2)*512 + c
//   [2560,10752)   : 4x4 scale, (i4*4+j4)*512 + c
//   [10752,43520)  : 8x8 scale, (i8*8+j8)*512 + c
// All bin sizes divide 64 evenly, so uniform bins (last-bin-extends is a no-op).
//
// Two dispatches (single-kernel cross-block combine regressed 47->131 us:
// device-scope fences force per-XCD L2 writeback on gfx950).
// R5->R6: kernel 1 split by channel-half -> 1024 blocks, 16 waves/CU
// (occupancy probe: is the stream latency-limited or BW-saturated?).

#define C_F4 128          // 512 channels / 4
#define ROW_OUT 43520     // 85 * 512
#define S8_OFF 10752
#define S4_OFF 2560
#define S2_OFF 512

typedef float vf4 __attribute__((ext_vector_type(4)));

static __device__ __forceinline__ vf4 vmax(vf4 a, vf4 b) {
    vf4 r;
    r.x = fmaxf(a.x, b.x);
    r.y = fmaxf(a.y, b.y);
    r.z = fmaxf(a.z, b.z);
    r.w = fmaxf(a.w, b.w);
    return r;
}

// Kernel 1: one block per (b, i4, j4, chalf) = 1024 blocks x 256 threads.
// Thread = (s in 0..3: 4-row band of the 16-row patch, c4i in 0..63: f4 slot
// within this block's 256-channel half). Each thread: 64 loads -> two partial
// w-bin maxes; LDS combines band pairs into the four s8 bins and the s4 bin.
__global__ __launch_bounds__(256) void spp_pool84(const float* __restrict__ x,
                                                  float* __restrict__ out) {
    const int blk = blockIdx.x;            // 0..1023
    const int b     = blk >> 5;
    const int rem   = blk & 31;
    const int i4    = rem >> 3;
    const int j4    = (rem >> 1) & 3;
    const int chalf = rem & 1;
    const int tid = threadIdx.x;           // 0..255
    const int s   = tid >> 6;              // band 0..3 (rows 4s..4s+3)
    const int c4i = tid & 63;
    const int c4g = chalf * 64 + c4i;      // global f4 channel slot 0..127

    const int row0 = i4 * 16 + s * 4;
    const vf4* src = reinterpret_cast<const vf4*>(x)
                   + (size_t)((b * 64 + row0) * 64 + j4 * 16) * C_F4 + c4g;
    // vf4 strides: next col = 128, next row = 64*128 = 8192

    vf4 m0 = src[0];            // cols 0..7  (j8 = 2*j4)
    vf4 m1 = src[8 * 128];      // cols 8..15 (j8 = 2*j4+1)
    #pragma unroll
    for (int h = 0; h < 4; ++h) {
        #pragma unroll
        for (int w = 0; w < 8; ++w) {
            if (h == 0 && w == 0) continue;
            m0 = vmax(m0, src[h * 8192 + w * 128]);
            m1 = vmax(m1, src[h * 8192 + (w + 8) * 128]);
        }
    }

    __shared__ vf4 ls0[4][64];
    __shared__ vf4 ls1[4][64];
    ls0[s][c4i] = m0;
    ls1[s][c4i] = m1;
    __syncthreads();

    float* row = out + (size_t)b * ROW_OUT;
    if (s < 2) {
        // band pair (2s, 2s+1) -> bin row i8 = 2*i4 + s
        const int i8 = 2 * i4 + s;
        const int j8 = 2 * j4;
        vf4 bin0 = vmax(ls0[2 * s][c4i], ls0[2 * s + 1][c4i]);
        vf4 bin1 = vmax(ls1[2 * s][c4i], ls1[2 * s + 1][c4i]);
        __builtin_nontemporal_store(bin0,
            reinterpret_cast<vf4*>(row + S8_OFF + (i8 * 8 + j8) * 512) + c4g);
        __builtin_nontemporal_store(bin1,
            reinterpret_cast<vf4*>(row + S8_OFF + (i8 * 8 + j8 + 1) * 512) + c4g);
        ls0[s][c4i] = vmax(bin0, bin1);    // s4 partial
    }
    __syncthreads();
    if (s == 0) {
        vf4 v4 = vmax(ls0[0][c4i], ls0[1][c4i]);
        reinterpret_cast<vf4*>(row + S4_OFF + (i4 * 4 + j4) * 512)[c4g] = v4;
    }
}

// Kernel 2: derive 2x2 / 1x1 from the 4x4 scale (1 MB, cache-hot).
// One block per batch, 512 threads = (quadrant q, c4); 4 loads per thread.
__global__ __launch_bounds__(512) void spp_tail(float* __restrict__ out) {
    const int b   = blockIdx.x;           // 0..31
    const int tid = threadIdx.x;          // 0..511
    const int q   = tid >> 7;             // quadrant 0..3
    const int c4  = tid & 127;
    const int i2  = q >> 1;
    const int j2  = q & 1;

    float* row = out + (size_t)b * ROW_OUT;
    const vf4* p4 = reinterpret_cast<const vf4*>(row + S4_OFF) + c4;

    vf4 m =     p4[((2 * i2)     * 4 + 2 * j2)     * C_F4];
    m = vmax(m, p4[((2 * i2)     * 4 + 2 * j2 + 1) * C_F4]);
    m = vmax(m, p4[((2 * i2 + 1) * 4 + 2 * j2)     * C_F4]);
    m = vmax(m, p4[((2 * i2 + 1) * 4 + 2 * j2 + 1) * C_F4]);

    reinterpret_cast<vf4*>(row + S2_OFF + q * 512)[c4] = m;

    __shared__ vf4 ls[4][128];
    ls[q][c4] = m;
    __syncthreads();
    if (q == 0) {
        vf4 v1 = vmax(vmax(ls[0][c4], ls[1][c4]),
                      vmax(ls[2][c4], ls[3][c4]));
        reinterpret_cast<vf4*>(row)[c4] = v1;
    }
}

extern "C" void kernel_launch(void* const* d_in, const int* in_sizes, int n_in,
                              void* d_out, int out_size, void* d_ws, size_t ws_size,
                              hipStream_t stream) {
    const float* x = (const float*)d_in[0];
    float* out = (float*)d_out;

    spp_pool84<<<1024, 256, 0, stream>>>(x, out);
    spp_tail<<<32, 512, 0, stream>>>(out);
}